// Round 4
// baseline (271.103 us; speedup 1.0000x reference)
//
#include <hip/hip_runtime.h>
#include <math.h>

typedef _Float16 f16;
typedef _Float16 f16x8 __attribute__((ext_vector_type(8)));
typedef float    f32x16 __attribute__((ext_vector_type(16)));
typedef unsigned int uint;

#define B_Q     1024
#define DIM     128
#define N_KEYS  100000
#define N_CLS   1000
#define QSCALE  11.541560327111707f /* 8/ln2: fold beta*log2(e) into queries */

// ---- label histogram (LDS-reduced) ----
__global__ void k_hist(const int* __restrict__ labels, uint* __restrict__ ghist) {
    __shared__ uint lh[N_CLS];
    for (int i = threadIdx.x; i < N_CLS; i += blockDim.x) lh[i] = 0;
    __syncthreads();
    const int stride = gridDim.x * blockDim.x;
    for (int i = blockIdx.x * blockDim.x + threadIdx.x; i < N_KEYS; i += stride)
        atomicAdd(&lh[labels[i]], 1u);
    __syncthreads();
    for (int i = threadIdx.x; i < N_CLS; i += blockDim.x)
        if (lh[i]) atomicAdd(&ghist[i], lh[i]);
}

// ---- exclusive scan over 1000 bins (single 1024-thread block) ----
__global__ void k_scan(const uint* __restrict__ ghist, uint* __restrict__ offs,
                       uint* __restrict__ cursor) {
    __shared__ uint s[1024];
    const int t = threadIdx.x;
    const uint v = (t < N_CLS) ? ghist[t] : 0u;
    s[t] = v; __syncthreads();
    for (int o = 1; o < 1024; o <<= 1) {
        const uint x = (t >= o) ? s[t - o] : 0u;
        __syncthreads();
        s[t] += x;
        __syncthreads();
    }
    if (t < N_CLS) { const uint e = s[t] - v; offs[t] = e; cursor[t] = e; }
    if (t == 1023) offs[N_CLS] = s[1023];
}

// ---- counting-sort scatter fused with normalize + f16 convert (1 wave/key) ----
__global__ void k_sortkeys(const float* __restrict__ km, const int* __restrict__ labels,
                           uint* __restrict__ cursor, f16* __restrict__ kf) {
    const int gid  = blockIdx.x * blockDim.x + threadIdx.x;
    const int n    = gid >> 6;
    const int lane = threadIdx.x & 63;
    if (n >= N_KEYS) return;
    const float* row = km + (size_t)n * DIM;
    const float a = row[lane];
    const float b = row[lane + 64];
    float ss = a * a + b * b;
    #pragma unroll
    for (int o = 32; o >= 1; o >>= 1) ss += __shfl_xor(ss, o);
    const float rn = 1.0f / fmaxf(sqrtf(ss), 1e-12f);
    int pos = 0;
    if (lane == 0) pos = (int)atomicAdd(&cursor[labels[n]], 1u);
    pos = __shfl(pos, 0);
    f16* dst = kf + (size_t)pos * DIM;
    dst[lane]      = (f16)(a * rn);
    dst[lane + 64] = (f16)(b * rn);
}

// ---- query prep: normalize, fold QSCALE, f16 (1 wave/row) ----
__global__ void k_prepq(const float* __restrict__ src, f16* __restrict__ dst) {
    const int gid  = blockIdx.x * blockDim.x + threadIdx.x;
    const int wid  = gid >> 6;
    const int lane = threadIdx.x & 63;
    if (wid >= B_Q) return;
    const float* row = src + (size_t)wid * DIM;
    const float a = row[lane];
    const float b = row[lane + 64];
    float ss = a * a + b * b;
    #pragma unroll
    for (int o = 32; o >= 1; o >>= 1) ss += __shfl_xor(ss, o);
    const float rn = QSCALE / fmaxf(sqrtf(ss), 1e-12f);
    f16* drow = dst + (size_t)wid * DIM;
    drow[lane]      = (f16)(a * rn);
    drow[lane + 64] = (f16)(b * rn);
}

// ---- main: block = (class, 512 queries). Double-buffered key tiles, 2-deep
// global prefetch, B-frags read once per tile and reused for both q-subtiles.
// Wave-tile 32q x 32k, v_mfma_f32_32x32x16_f16, K=128 (8 mfma per q-subtile).
// A: lane row=l&31, k = 16*kk + 8*lhi + j.  B: col=l&31, same k.
// C/D: col(key)=l&31, row(q)=(r&3)+8*(r>>2)+4*lhi.
#define SLOT(key, s) ((((s) ^ ((key) & 15)) + 2 * ((key) >> 4)) & 15)
__global__ __launch_bounds__(512, 2)
void class_gemm2(const f16* __restrict__ kf, const f16* __restrict__ qf,
                 const uint* __restrict__ offs, float* __restrict__ out_t) {
    __shared__ __align__(16) f16 kt[2][32 * DIM];   // 2 x 8 KB swizzled key tiles

    const int tid  = threadIdx.x;
    const int wid  = tid >> 6;
    const int lane = tid & 63;
    const int l31  = lane & 31;
    const int lhi  = lane >> 5;
    const int c    = blockIdx.x;
    const int qb   = blockIdx.y * 512;

    const int beg = (int)offs[c];
    const int end = (int)offs[c + 1];
    const int cnt = end - beg;

    float* otc = out_t + (size_t)c * B_Q + qb;
    if (cnt == 0) { otc[tid] = 0.0f; return; }      // uniform early-out

    // A fragments: 2 q-subtiles of 256, wave owns 32 q in each
    f16x8 A[2][8];
    #pragma unroll
    for (int qt = 0; qt < 2; ++qt) {
        const f16* qp = qf + (size_t)(qb + qt * 256 + wid * 32 + l31) * DIM + lhi * 8;
        #pragma unroll
        for (int kk = 0; kk < 8; ++kk) A[qt][kk] = *(const f16x8*)(qp + kk * 16);
    }

    const int skey  = tid >> 4;       // 32 keys
    const int sslot = tid & 15;       // 16 x 16B slots per key row
    const int nt    = (cnt + 31) >> 5;

    // prologue: stage tile 0, prefetch tile 1
    f16x8 sreg = *(const f16x8*)(kf + (size_t)min(beg + skey, end - 1) * DIM + sslot * 8);
    *(f16x8*)(&kt[0][skey * DIM + SLOT(skey, sslot) * 8]) = sreg;
    if (nt > 1)
        sreg = *(const f16x8*)(kf + (size_t)min(beg + 32 + skey, end - 1) * DIM + sslot * 8);

    float sums[2][16];
    #pragma unroll
    for (int qt = 0; qt < 2; ++qt)
        #pragma unroll
        for (int r = 0; r < 16; ++r) sums[qt][r] = 0.0f;

    for (int t = 0; t < nt; ++t) {
        __syncthreads();                           // kt[t&1] ready; old reads done
        const f16* kb = &kt[t & 1][l31 * DIM];
        f16x8 B[8];
        #pragma unroll
        for (int kk = 0; kk < 8; ++kk)
            B[kk] = *(const f16x8*)(kb + SLOT(l31, lhi + 2 * kk) * 8);
        if (t + 1 < nt) {
            *(f16x8*)(&kt[(t + 1) & 1][skey * DIM + SLOT(skey, sslot) * 8]) = sreg;
            if (t + 2 < nt)
                sreg = *(const f16x8*)(kf + (size_t)min(beg + (t + 2) * 32 + skey, end - 1) * DIM + sslot * 8);
        }
        f32x16 c0 = {}, c1 = {};
        #pragma unroll
        for (int kk = 0; kk < 8; ++kk) {
            c0 = __builtin_amdgcn_mfma_f32_32x32x16_f16(A[0][kk], B[kk], c0, 0, 0, 0);
            c1 = __builtin_amdgcn_mfma_f32_32x32x16_f16(A[1][kk], B[kk], c1, 0, 0, 0);
        }
        if (t * 32 + l31 < cnt) {
            #pragma unroll
            for (int r = 0; r < 16; ++r) {
                sums[0][r] += __builtin_amdgcn_exp2f(c0[r]);
                sums[1][r] += __builtin_amdgcn_exp2f(c1[r]);
            }
        }
    }

    // reduce over 32 key-columns, store coalesced-ish into out_t[c][...]
    #pragma unroll
    for (int qt = 0; qt < 2; ++qt) {
        #pragma unroll
        for (int r = 0; r < 16; ++r) {
            float s = sums[qt][r];
            s += __shfl_xor(s, 1);  s += __shfl_xor(s, 2);  s += __shfl_xor(s, 4);
            s += __shfl_xor(s, 8);  s += __shfl_xor(s, 16);
            if (l31 == 0) {
                const int row = (r & 3) + 8 * (r >> 2) + 4 * lhi;
                otc[qt * 256 + wid * 32 + row] = s;
            }
        }
    }
}

// ---- fused softmax-normalize + transpose: out[q][c] = out_t[c][q] / sum_c ----
__global__ __launch_bounds__(256)
void norm_transpose(const float* __restrict__ out_t, float* __restrict__ out) {
    __shared__ float tile[64 * 65];
    __shared__ float invq[64];
    __shared__ float psum4[4][64];
    const int tid  = threadIdx.x;
    const int w    = tid >> 6;
    const int lane = tid & 63;
    const int q0   = blockIdx.x * 64;

    // pass 1: per-query denominator over all classes
    float ps = 0.0f;
    for (int c = w; c < N_CLS; c += 4)
        ps += out_t[(size_t)c * B_Q + q0 + lane];
    psum4[w][lane] = ps;
    __syncthreads();
    if (w == 0)
        invq[lane] = 1.0f / (psum4[0][lane] + psum4[1][lane] + psum4[2][lane] + psum4[3][lane]);

    // pass 2: scale + LDS transpose + coalesced writes
    for (int cc = 0; cc < 16; ++cc) {
        __syncthreads();                 // invq ready / tile reuse safe
        for (int i = w; i < 64; i += 4) {
            const int cidx = cc * 64 + i;
            const float v = (cidx < N_CLS) ? out_t[(size_t)cidx * B_Q + q0 + lane] : 0.0f;
            tile[lane * 65 + i] = v * invq[lane];
        }
        __syncthreads();
        #pragma unroll
        for (int j = 0; j < 16; ++j) {
            const int r    = w * 16 + j;
            const int cidx = cc * 64 + lane;
            if (cidx < N_CLS)
                out[(size_t)(q0 + r) * N_CLS + cidx] = tile[r * 65 + lane];
        }
    }
}

extern "C" void kernel_launch(void* const* d_in, const int* in_sizes, int n_in,
                              void* d_out, int out_size, void* d_ws, size_t ws_size,
                              hipStream_t stream) {
    const float* qm     = (const float*)d_in[0];
    const float* km     = (const float*)d_in[1];
    const int*   labels = (const int*)d_in[2];
    float* out = (float*)d_out;

    f16*   kf     = (f16*)d_ws;                        // [100000][128] f16, class-sorted
    f16*   qf     = kf + (size_t)N_KEYS * DIM;         // [1024][128] f16
    float* out_t  = (float*)(qf + (size_t)B_Q * DIM);  // [1000][1024] f32
    uint*  ghist  = (uint*)(out_t + (size_t)N_CLS * B_Q);
    uint*  offs   = ghist + N_CLS;                     // [1001]
    uint*  cursor = offs + N_CLS + 1;                  // [1000]

    hipMemsetAsync(ghist, 0, N_CLS * sizeof(uint), stream);

    hipLaunchKernelGGL(k_hist, dim3(128), dim3(256), 0, stream, labels, ghist);
    hipLaunchKernelGGL(k_scan, dim3(1), dim3(1024), 0, stream, ghist, offs, cursor);
    hipLaunchKernelGGL(k_sortkeys, dim3((N_KEYS * 64) / 256), dim3(256), 0, stream,
                       km, labels, cursor, kf);
    hipLaunchKernelGGL(k_prepq, dim3((B_Q * 64) / 256), dim3(256), 0, stream, qm, qf);

    hipLaunchKernelGGL(class_gemm2, dim3(N_CLS, B_Q / 512), dim3(512), 0, stream,
                       kf, qf, offs, out_t);

    hipLaunchKernelGGL(norm_transpose, dim3(B_Q / 64), dim3(256), 0, stream, out_t, out);
}

// Round 5
// 169.646 us; speedup vs baseline: 1.5981x; 1.5981x over previous
//
#include <hip/hip_runtime.h>
#include <math.h>

typedef _Float16 f16;
typedef _Float16 f16x8 __attribute__((ext_vector_type(8)));
typedef float    f32x16 __attribute__((ext_vector_type(16)));
typedef unsigned int uint;

#define B_Q     1024
#define DIM     128
#define N_KEYS  100000
#define N_CLS   1000
#define QSCALE  11.541560327111707f /* 8/ln2: fold beta*log2(e) into queries */
#define CSUM    40                  /* classes per qsum block: 25 blocks */
#define NCB     (N_CLS / CSUM)      /* 25 */

// ---- label histogram (LDS-reduced) ----
__global__ void k_hist(const int* __restrict__ labels, uint* __restrict__ ghist) {
    __shared__ uint lh[N_CLS];
    for (int i = threadIdx.x; i < N_CLS; i += blockDim.x) lh[i] = 0;
    __syncthreads();
    const int stride = gridDim.x * blockDim.x;
    for (int i = blockIdx.x * blockDim.x + threadIdx.x; i < N_KEYS; i += stride)
        atomicAdd(&lh[labels[i]], 1u);
    __syncthreads();
    for (int i = threadIdx.x; i < N_CLS; i += blockDim.x)
        if (lh[i]) atomicAdd(&ghist[i], lh[i]);
}

// ---- exclusive scan over 1000 bins (single 1024-thread block) ----
__global__ void k_scan(const uint* __restrict__ ghist, uint* __restrict__ offs,
                       uint* __restrict__ cursor) {
    __shared__ uint s[1024];
    const int t = threadIdx.x;
    const uint v = (t < N_CLS) ? ghist[t] : 0u;
    s[t] = v; __syncthreads();
    for (int o = 1; o < 1024; o <<= 1) {
        const uint x = (t >= o) ? s[t - o] : 0u;
        __syncthreads();
        s[t] += x;
        __syncthreads();
    }
    if (t < N_CLS) { const uint e = s[t] - v; offs[t] = e; cursor[t] = e; }
    if (t == 1023) offs[N_CLS] = s[1023];
}

// ---- counting-sort scatter fused with normalize + f16 convert (1 wave/key) ----
__global__ void k_sortkeys(const float* __restrict__ km, const int* __restrict__ labels,
                           uint* __restrict__ cursor, f16* __restrict__ kf) {
    const int gid  = blockIdx.x * blockDim.x + threadIdx.x;
    const int n    = gid >> 6;
    const int lane = threadIdx.x & 63;
    if (n >= N_KEYS) return;
    const float* row = km + (size_t)n * DIM;
    const float a = row[lane];
    const float b = row[lane + 64];
    float ss = a * a + b * b;
    #pragma unroll
    for (int o = 32; o >= 1; o >>= 1) ss += __shfl_xor(ss, o);
    const float rn = 1.0f / fmaxf(sqrtf(ss), 1e-12f);
    int pos = 0;
    if (lane == 0) pos = (int)atomicAdd(&cursor[labels[n]], 1u);
    pos = __shfl(pos, 0);
    f16* dst = kf + (size_t)pos * DIM;
    dst[lane]      = (f16)(a * rn);
    dst[lane + 64] = (f16)(b * rn);
}

// ---- query prep: normalize, fold QSCALE, f16 (1 wave/row) ----
__global__ void k_prepq(const float* __restrict__ src, f16* __restrict__ dst) {
    const int gid  = blockIdx.x * blockDim.x + threadIdx.x;
    const int wid  = gid >> 6;
    const int lane = threadIdx.x & 63;
    if (wid >= B_Q) return;
    const float* row = src + (size_t)wid * DIM;
    const float a = row[lane];
    const float b = row[lane + 64];
    float ss = a * a + b * b;
    #pragma unroll
    for (int o = 32; o >= 1; o >>= 1) ss += __shfl_xor(ss, o);
    const float rn = QSCALE / fmaxf(sqrtf(ss), 1e-12f);
    f16* drow = dst + (size_t)wid * DIM;
    drow[lane]      = (f16)(a * rn);
    drow[lane + 64] = (f16)(b * rn);
}

// ---- main: block = (class, 512 queries). Double-buffered key tiles, 2-deep
// global prefetch, B-frags read once per tile and reused for both q-subtiles.
#define SLOT(key, s) ((((s) ^ ((key) & 15)) + 2 * ((key) >> 4)) & 15)
__global__ __launch_bounds__(512, 2)
void class_gemm2(const f16* __restrict__ kf, const f16* __restrict__ qf,
                 const uint* __restrict__ offs, float* __restrict__ out_t) {
    __shared__ __align__(16) f16 kt[2][32 * DIM];   // 2 x 8 KB swizzled key tiles

    const int tid  = threadIdx.x;
    const int wid  = tid >> 6;
    const int lane = tid & 63;
    const int l31  = lane & 31;
    const int lhi  = lane >> 5;
    const int c    = blockIdx.x;
    const int qb   = blockIdx.y * 512;

    const int beg = (int)offs[c];
    const int end = (int)offs[c + 1];
    const int cnt = end - beg;

    float* otc = out_t + (size_t)c * B_Q + qb;
    if (cnt == 0) { otc[tid] = 0.0f; return; }      // uniform early-out

    // A fragments: 2 q-subtiles of 256, wave owns 32 q in each
    f16x8 A[2][8];
    #pragma unroll
    for (int qt = 0; qt < 2; ++qt) {
        const f16* qp = qf + (size_t)(qb + qt * 256 + wid * 32 + l31) * DIM + lhi * 8;
        #pragma unroll
        for (int kk = 0; kk < 8; ++kk) A[qt][kk] = *(const f16x8*)(qp + kk * 16);
    }

    const int skey  = tid >> 4;       // 32 keys
    const int sslot = tid & 15;       // 16 x 16B slots per key row
    const int nt    = (cnt + 31) >> 5;

    // prologue: stage tile 0, prefetch tile 1
    f16x8 sreg = *(const f16x8*)(kf + (size_t)min(beg + skey, end - 1) * DIM + sslot * 8);
    *(f16x8*)(&kt[0][skey * DIM + SLOT(skey, sslot) * 8]) = sreg;
    if (nt > 1)
        sreg = *(const f16x8*)(kf + (size_t)min(beg + 32 + skey, end - 1) * DIM + sslot * 8);

    float sums[2][16];
    #pragma unroll
    for (int qt = 0; qt < 2; ++qt)
        #pragma unroll
        for (int r = 0; r < 16; ++r) sums[qt][r] = 0.0f;

    for (int t = 0; t < nt; ++t) {
        __syncthreads();                           // kt[t&1] ready; old reads done
        const f16* kb = &kt[t & 1][l31 * DIM];
        f16x8 B[8];
        #pragma unroll
        for (int kk = 0; kk < 8; ++kk)
            B[kk] = *(const f16x8*)(kb + SLOT(l31, lhi + 2 * kk) * 8);
        if (t + 1 < nt) {
            *(f16x8*)(&kt[(t + 1) & 1][skey * DIM + SLOT(skey, sslot) * 8]) = sreg;
            if (t + 2 < nt)
                sreg = *(const f16x8*)(kf + (size_t)min(beg + (t + 2) * 32 + skey, end - 1) * DIM + sslot * 8);
        }
        f32x16 c0 = {}, c1 = {};
        #pragma unroll
        for (int kk = 0; kk < 8; ++kk) {
            c0 = __builtin_amdgcn_mfma_f32_32x32x16_f16(A[0][kk], B[kk], c0, 0, 0, 0);
            c1 = __builtin_amdgcn_mfma_f32_32x32x16_f16(A[1][kk], B[kk], c1, 0, 0, 0);
        }
        if (t * 32 + l31 < cnt) {
            #pragma unroll
            for (int r = 0; r < 16; ++r) {
                sums[0][r] += __builtin_amdgcn_exp2f(c0[r]);
                sums[1][r] += __builtin_amdgcn_exp2f(c1[r]);
            }
        }
    }

    // reduce over 32 key-columns, store into out_t[c][...]
    #pragma unroll
    for (int qt = 0; qt < 2; ++qt) {
        #pragma unroll
        for (int r = 0; r < 16; ++r) {
            float s = sums[qt][r];
            s += __shfl_xor(s, 1);  s += __shfl_xor(s, 2);  s += __shfl_xor(s, 4);
            s += __shfl_xor(s, 8);  s += __shfl_xor(s, 16);
            if (l31 == 0) {
                const int row = (r & 3) + 8 * (r >> 2) + 4 * lhi;
                otc[qt * 256 + wid * 32 + row] = s;
            }
        }
    }
}

// ---- epilogue 1: partial class-sums per query (25 blocks x 1024 thr) ----
__global__ __launch_bounds__(1024)
void k_qsum(const float* __restrict__ out_t, float* __restrict__ partial) {
    const int cb = blockIdx.x;
    const int q  = threadIdx.x;
    const float* p = out_t + (size_t)cb * CSUM * B_Q + q;
    float s = 0.0f;
    #pragma unroll 8
    for (int i = 0; i < CSUM; ++i) s += p[(size_t)i * B_Q];
    partial[cb * B_Q + q] = s;
}

// ---- epilogue 2: 64x64 scaled transpose tiles (16 x 16 blocks) ----
__global__ __launch_bounds__(256)
void k_norm_t(const float* __restrict__ out_t, const float* __restrict__ partial,
              float* __restrict__ out) {
    __shared__ float tile[64 * 65];
    __shared__ float invq[64];
    const int tid  = threadIdx.x;
    const int w    = tid >> 6;
    const int lane = tid & 63;
    const int q0   = blockIdx.x * 64;
    const int c0   = blockIdx.y * 64;

    if (tid < 64) {
        float s = 0.0f;
        #pragma unroll
        for (int cb = 0; cb < NCB; ++cb) s += partial[cb * B_Q + q0 + tid];
        invq[tid] = 1.0f / s;
    }

    // read 64 class-rows (coalesced over q), store transposed-ready in LDS
    #pragma unroll
    for (int i = 0; i < 16; ++i) {
        const int cidx = c0 + w * 16 + i;
        const float v = (cidx < N_CLS) ? out_t[(size_t)cidx * B_Q + q0 + lane] : 0.0f;
        tile[lane * 65 + w * 16 + i] = v;
    }
    __syncthreads();
    // write out[q][c], coalesced over c
    #pragma unroll
    for (int j = 0; j < 16; ++j) {
        const int r    = w * 16 + j;
        const int cidx = c0 + lane;
        if (cidx < N_CLS)
            out[(size_t)(q0 + r) * N_CLS + cidx] = tile[r * 65 + lane] * invq[r];
    }
}

extern "C" void kernel_launch(void* const* d_in, const int* in_sizes, int n_in,
                              void* d_out, int out_size, void* d_ws, size_t ws_size,
                              hipStream_t stream) {
    const float* qm     = (const float*)d_in[0];
    const float* km     = (const float*)d_in[1];
    const int*   labels = (const int*)d_in[2];
    float* out = (float*)d_out;

    f16*   kf      = (f16*)d_ws;                        // [100000][128] f16, class-sorted
    f16*   qf      = kf + (size_t)N_KEYS * DIM;         // [1024][128] f16
    float* out_t   = (float*)(qf + (size_t)B_Q * DIM);  // [1000][1024] f32
    float* partial = out_t + (size_t)N_CLS * B_Q;       // [25][1024] f32
    uint*  ghist   = (uint*)(partial + NCB * B_Q);      // [1000]
    uint*  offs    = ghist + N_CLS;                     // [1001]
    uint*  cursor  = offs + N_CLS + 1;                  // [1000]

    hipMemsetAsync(ghist, 0, N_CLS * sizeof(uint), stream);

    hipLaunchKernelGGL(k_hist, dim3(128), dim3(256), 0, stream, labels, ghist);
    hipLaunchKernelGGL(k_scan, dim3(1), dim3(1024), 0, stream, ghist, offs, cursor);
    hipLaunchKernelGGL(k_sortkeys, dim3((N_KEYS * 64) / 256), dim3(256), 0, stream,
                       km, labels, cursor, kf);
    hipLaunchKernelGGL(k_prepq, dim3((B_Q * 64) / 256), dim3(256), 0, stream, qm, qf);

    hipLaunchKernelGGL(class_gemm2, dim3(N_CLS, B_Q / 512), dim3(512), 0, stream,
                       kf, qf, offs, out_t);

    hipLaunchKernelGGL(k_qsum, dim3(NCB), dim3(1024), 0, stream, out_t, partial);
    hipLaunchKernelGGL(k_norm_t, dim3(B_Q / 64, (N_CLS + 63) / 64), dim3(256), 0, stream,
                       out_t, partial, out);
}

// Round 6
// 140.468 us; speedup vs baseline: 1.9300x; 1.2077x over previous
//
#include <hip/hip_runtime.h>
#include <math.h>

typedef _Float16 f16;
typedef _Float16 f16x8 __attribute__((ext_vector_type(8)));
typedef float    f32x16 __attribute__((ext_vector_type(16)));
typedef unsigned int uint;
typedef unsigned short u16;

#define B_Q     1024
#define DIM     128
#define N_KEYS  100000
#define N_CLS   1000
#define NG      (N_KEYS / 32)   /* 3125 groups of 32 sorted keys */
#define KC      125             /* key chunks -> gridDim.y */
#define GPB     (NG / KC)       /* 25 groups per block */
#define QSCALE  11.541560327111707f /* 8/ln2: fold beta*log2(e) into queries */
#define CSUM    40
#define NCB     (N_CLS / CSUM)  /* 25 */

// ---- label histogram ----
__global__ void k_hist(const int* __restrict__ labels, uint* __restrict__ ghist) {
    __shared__ uint lh[N_CLS];
    for (int i = threadIdx.x; i < N_CLS; i += blockDim.x) lh[i] = 0;
    __syncthreads();
    const int stride = gridDim.x * blockDim.x;
    for (int i = blockIdx.x * blockDim.x + threadIdx.x; i < N_KEYS; i += stride)
        atomicAdd(&lh[labels[i]], 1u);
    __syncthreads();
    for (int i = threadIdx.x; i < N_CLS; i += blockDim.x)
        if (lh[i]) atomicAdd(&ghist[i], lh[i]);
}

// ---- exclusive scan -> cursor ----
__global__ void k_scan(const uint* __restrict__ ghist, uint* __restrict__ cursor) {
    __shared__ uint s[1024];
    const int t = threadIdx.x;
    const uint v = (t < N_CLS) ? ghist[t] : 0u;
    s[t] = v; __syncthreads();
    for (int o = 1; o < 1024; o <<= 1) {
        const uint x = (t >= o) ? s[t - o] : 0u;
        __syncthreads();
        s[t] += x;
        __syncthreads();
    }
    if (t < N_CLS) cursor[t] = s[t] - v;
}

// ---- fused prep: normalize rows, f16, scatter into MFMA-fragment order ----
// kf2/qf2 layout per 32-row group: [kk(8)][lane(64)][j(8)] f16; element
// (kk,lane,j) = row (lane&31), dim kk*16 + (lane>>5)*8 + j.
__global__ void k_prep(const float* __restrict__ qm, const float* __restrict__ km,
                       const int* __restrict__ labels, uint* __restrict__ cursor,
                       f16* __restrict__ kf2, f16* __restrict__ qf2,
                       u16* __restrict__ kcls) {
    const int gid  = blockIdx.x * blockDim.x + threadIdx.x;
    const int n    = gid >> 6;
    const int lane = threadIdx.x & 63;
    if (n >= N_KEYS + B_Q) return;
    const bool isq = n >= N_KEYS;
    const float* row = isq ? qm + (size_t)(n - N_KEYS) * DIM
                           : km + (size_t)n * DIM;
    const float a = row[lane];
    const float b = row[lane + 64];
    float ss = a * a + b * b;
    #pragma unroll
    for (int o = 32; o >= 1; o >>= 1) ss += __shfl_xor(ss, o);
    const float rn = (isq ? QSCALE : 1.0f) / fmaxf(sqrtf(ss), 1e-12f);

    int pos;
    if (isq) {
        pos = n - N_KEYS;
    } else {
        const int lab = labels[n];
        if (lane == 0) pos = (int)atomicAdd(&cursor[lab], 1u);
        pos = __shfl(pos, 0);
        if (lane == 0) kcls[pos] = (u16)lab;
    }

    const float va = a * rn, vb = b * rn;
    // piece p = lane&15 covers dims 8p..8p+7 ; gather via shuffles
    f16x8 hv;
    #pragma unroll
    for (int j = 0; j < 8; ++j) {
        const int src = (lane & 15) * 8 + j;        // 0..127
        const float xa = __shfl(va, src & 63);
        const float xb = __shfl(vb, src & 63);      // src>=64: src&63 == src-64
        hv[j] = (f16)((src < 64) ? xa : xb);
    }
    if (lane < 16) {
        f16* dst = isq ? qf2 : kf2;
        const int kk  = lane >> 1;
        const int lhi = lane & 1;
        *(f16x8*)(dst + (size_t)(pos >> 5) * 4096 + kk * 512 +
                  ((lhi << 5) + (pos & 31)) * 8) = hv;
    }
}

// ---- main: 256 thr / 4 waves; wave = 2 q-subtiles x 32k; fragment-order LDS;
// per-class register sums, butterfly flush -> atomicAdd out_t[c][q].
#define FLUSH(C) {                                                            \
    _Pragma("unroll")                                                         \
    for (int r = 0; r < 16; ++r) {                                            \
        float t0 = sums0[r], t1 = sums1[r];                                   \
        t0 += __shfl_xor(t0,1); t0 += __shfl_xor(t0,2); t0 += __shfl_xor(t0,4);\
        t0 += __shfl_xor(t0,8); t0 += __shfl_xor(t0,16);                      \
        t1 += __shfl_xor(t1,1); t1 += __shfl_xor(t1,2); t1 += __shfl_xor(t1,4);\
        t1 += __shfl_xor(t1,8); t1 += __shfl_xor(t1,16);                      \
        const int row = (r & 3) + 8 * (r >> 2) + 4 * lhi;                     \
        if (l31 == row) {                                                     \
            atomicAdd(&out_t[(size_t)(C) * B_Q + q00 + row], t0);             \
            atomicAdd(&out_t[(size_t)(C) * B_Q + q01 + row], t1);             \
        }                                                                     \
    } }
#define ZEROSUMS { _Pragma("unroll") for (int r=0;r<16;++r){sums0[r]=0.f;sums1[r]=0.f;} }

__global__ __launch_bounds__(256, 2)
void class_gemm3(const f16* __restrict__ kf2, const f16* __restrict__ qf2,
                 const u16* __restrict__ kcls, float* __restrict__ out_t) {
    __shared__ __align__(16) f16 kt[2][4096];   // 2 x 8 KB fragment-order tiles

    const int tid  = threadIdx.x;
    const int w    = tid >> 6;
    const int lane = tid & 63;
    const int l31  = lane & 31;
    const int lhi  = lane >> 5;
    const int qb   = blockIdx.x;      // 0..3 (fast dim: chunk-sharers adjacent)
    const int kc   = blockIdx.y;      // 0..124
    const int g0   = kc * GPB;

    // A fragments: wave w owns queries qb*256 + w*64 + {0..63}
    f16x8 A0[8], A1[8];
    {
        const f16* qa = qf2 + (size_t)(qb * 8 + w * 2) * 4096 + lane * 8;
        #pragma unroll
        for (int kk = 0; kk < 8; ++kk) {
            A0[kk] = *(const f16x8*)(qa + kk * 512);
            A1[kk] = *(const f16x8*)(qa + 4096 + kk * 512);
        }
    }
    const int q00 = qb * 256 + w * 64;
    const int q01 = q00 + 32;

    // prologue: stage tile 0 direct, prefetch tile 1 into regs
    {
        const f16* src = kf2 + (size_t)g0 * 4096 + tid * 8;
        *(f16x8*)(&kt[0][tid * 8])        = *(const f16x8*)(src);
        *(f16x8*)(&kt[0][2048 + tid * 8]) = *(const f16x8*)(src + 2048);
    }
    f16x8 s0 = {}, s1 = {};
    {
        const f16* src = kf2 + (size_t)(g0 + 1) * 4096 + tid * 8;
        s0 = *(const f16x8*)(src);
        s1 = *(const f16x8*)(src + 2048);
    }

    float sums0[16], sums1[16];
    ZEROSUMS;
    int cur = -1;

    for (int i = 0; i < GPB; ++i) {
        const int g = g0 + i;
        // per-lane class metadata for this group (<= 2 runs guaranteed)
        const int  cl    = kcls[g * 32 + l31];
        const int  ca    = __shfl(cl, 0);
        const uint dm    = (uint)(__ballot(cl != ca) & 0xffffffffull);
        const int  split = dm ? (__ffs(dm) - 1) : 32;
        const int  cb    = (split < 32) ? __shfl(cl, split) : ca;

        __syncthreads();                       // kt[i&1] ready; old reads done
        if (i + 1 < GPB) {                     // write landed tile, issue i+2
            *(f16x8*)(&kt[(i + 1) & 1][tid * 8])        = s0;
            *(f16x8*)(&kt[(i + 1) & 1][2048 + tid * 8]) = s1;
            if (i + 2 < GPB) {
                const f16* src = kf2 + (size_t)(g + 2) * 4096 + tid * 8;
                s0 = *(const f16x8*)(src);
                s1 = *(const f16x8*)(src + 2048);
            }
        }

        // B frags: lane-linear conflict-free ds_read_b128, reused by 2 subtiles
        f32x16 c0 = {}, c1 = {};
        const f16* kb = kt[i & 1];
        #pragma unroll
        for (int kk = 0; kk < 8; ++kk) {
            const f16x8 Bf = *(const f16x8*)(kb + kk * 512 + lane * 8);
            c0 = __builtin_amdgcn_mfma_f32_32x32x16_f16(A0[kk], Bf, c0, 0, 0, 0);
            c1 = __builtin_amdgcn_mfma_f32_32x32x16_f16(A1[kk], Bf, c1, 0, 0, 0);
        }

        if (ca != cur) {                       // new class starts this group
            if (cur >= 0) FLUSH(cur);
            ZEROSUMS;
            cur = ca;
        }
        if (split == 32) {
            #pragma unroll
            for (int r = 0; r < 16; ++r) {
                sums0[r] += __builtin_amdgcn_exp2f(c0[r]);
                sums1[r] += __builtin_amdgcn_exp2f(c1[r]);
            }
        } else {                               // boundary group: 2 runs
            const bool lo = l31 < split;
            #pragma unroll
            for (int r = 0; r < 16; ++r) {
                if (lo) { sums0[r] += __builtin_amdgcn_exp2f(c0[r]);
                          sums1[r] += __builtin_amdgcn_exp2f(c1[r]); }
            }
            FLUSH(cur);
            ZEROSUMS;
            cur = cb;
            #pragma unroll
            for (int r = 0; r < 16; ++r) {
                if (!lo) { sums0[r] += __builtin_amdgcn_exp2f(c0[r]);
                           sums1[r] += __builtin_amdgcn_exp2f(c1[r]); }
            }
        }
    }
    if (cur >= 0) FLUSH(cur);
}

// ---- epilogue 1: partial class-sums per query ----
__global__ __launch_bounds__(1024)
void k_qsum(const float* __restrict__ out_t, float* __restrict__ partial) {
    const int cb = blockIdx.x;
    const int q  = threadIdx.x;
    const float* p = out_t + (size_t)cb * CSUM * B_Q + q;
    float s = 0.0f;
    #pragma unroll 8
    for (int i = 0; i < CSUM; ++i) s += p[(size_t)i * B_Q];
    partial[cb * B_Q + q] = s;
}

// ---- epilogue 2: 64x64 scaled transpose tiles ----
__global__ __launch_bounds__(256)
void k_norm_t(const float* __restrict__ out_t, const float* __restrict__ partial,
              float* __restrict__ out) {
    __shared__ float tile[64 * 65];
    __shared__ float invq[64];
    const int tid  = threadIdx.x;
    const int w    = tid >> 6;
    const int lane = tid & 63;
    const int q0   = blockIdx.x * 64;
    const int c0   = blockIdx.y * 64;

    if (tid < 64) {
        float s = 0.0f;
        #pragma unroll
        for (int cb = 0; cb < NCB; ++cb) s += partial[cb * B_Q + q0 + tid];
        invq[tid] = 1.0f / s;
    }
    #pragma unroll
    for (int i = 0; i < 16; ++i) {
        const int cidx = c0 + w * 16 + i;
        const float v = (cidx < N_CLS) ? out_t[(size_t)cidx * B_Q + q0 + lane] : 0.0f;
        tile[lane * 65 + w * 16 + i] = v;
    }
    __syncthreads();
    #pragma unroll
    for (int j = 0; j < 16; ++j) {
        const int r    = w * 16 + j;
        const int cidx = c0 + lane;
        if (cidx < N_CLS)
            out[(size_t)(q0 + r) * N_CLS + cidx] = tile[r * 65 + lane] * invq[r];
    }
}

extern "C" void kernel_launch(void* const* d_in, const int* in_sizes, int n_in,
                              void* d_out, int out_size, void* d_ws, size_t ws_size,
                              hipStream_t stream) {
    const float* qm     = (const float*)d_in[0];
    const float* km     = (const float*)d_in[1];
    const int*   labels = (const int*)d_in[2];
    float* out = (float*)d_out;

    char* p = (char*)d_ws;
    f16*   kf2     = (f16*)p;            p += (size_t)N_KEYS * DIM * 2;   // 25.6 MB
    f16*   qf2     = (f16*)p;            p += (size_t)B_Q * DIM * 2;      // 256 KB
    float* out_t   = (float*)p;          p += (size_t)N_CLS * B_Q * 4;    // 4.1 MB
    float* partial = (float*)p;          p += (size_t)NCB * B_Q * 4;      // 100 KB
    uint*  ghist   = (uint*)p;           p += N_CLS * 4;
    uint*  cursor  = (uint*)p;           p += N_CLS * 4;
    u16*   kcls    = (u16*)p;            p += N_KEYS * 2;                 // 200 KB

    hipMemsetAsync(ghist, 0, N_CLS * sizeof(uint), stream);
    hipMemsetAsync(out_t, 0, (size_t)N_CLS * B_Q * sizeof(float), stream);

    hipLaunchKernelGGL(k_hist, dim3(128), dim3(256), 0, stream, labels, ghist);
    hipLaunchKernelGGL(k_scan, dim3(1), dim3(1024), 0, stream, ghist, cursor);

    const int prows = N_KEYS + B_Q;                 // keys + queries, 1 wave each
    hipLaunchKernelGGL(k_prep, dim3((prows * 64 + 255) / 256), dim3(256), 0, stream,
                       qm, km, labels, cursor, kf2, qf2, kcls);

    hipLaunchKernelGGL(class_gemm3, dim3(4, KC), dim3(256), 0, stream,
                       kf2, qf2, kcls, out_t);

    hipLaunchKernelGGL(k_qsum, dim3(NCB), dim3(1024), 0, stream, out_t, partial);
    hipLaunchKernelGGL(k_norm_t, dim3(B_Q / 64, (N_CLS + 63) / 64), dim3(256), 0, stream,
                       out_t, partial, out);
}